// Round 6
// baseline (128.547 us; speedup 1.0000x reference)
//
#include <hip/hip_runtime.h>
#include <hip/hip_bf16.h>

typedef __bf16 bf16;
typedef __bf16 v8bf __attribute__((ext_vector_type(8)));
typedef __bf16 v4bf __attribute__((ext_vector_type(4)));
typedef float v4f __attribute__((ext_vector_type(4)));

#define HW 4096
#define CH 256
#define KC 32
#define RD 16
#define NB 2
#define BNEPS 1e-5f
#define VSTRIDE 4224

// ---------------- workspace byte offsets (~46.6 MiB) ----------------
#define OFF_MEAN   0u          // f32 [2][256]
#define OFF_WKB    4096u       // f32 [2][32][256] gate-folded Wk
#define OFF_QT     69632u      // bf16 [2][4096][32]
#define OFF_KT     593920u     // bf16 [2][4096][32]
#define OFF_BS1    1118208u    // bf16 [2][4096][32] pooled b1 (pre-scaled by w_gb/9)
#define OFF_BS2    1642496u    // bf16 [2][4096][32] pooled b2
#define OFF_VT     2166784u    // bf16 [2][256][VSTRIDE] V transposed (padded rows)
#define OFF_B1R    6492160u    // f32 [2][4096][32] raw relu(Wb1 x)
#define OFF_B2R    7540736u    // f32 [2][4096][32]
#define OFF_CTX    8589312u    // bf16 [2][4096][256]
#define OFF_PACC   12783616u   // bf16 [1024][64][256] split-K partial ctx
#define OFF_PL     46338048u   // f32 [1024*64] partial softmax denominators

// ---------------- K1: per-(b,c) spatial mean ----------------
__global__ __launch_bounds__(256) void k_mean(const float* __restrict__ x,
                                              float* __restrict__ mean) {
  int bc = blockIdx.x;                       // 0..511
  const float* px = x + (size_t)bc * HW;
  float s = 0.f;
  for (int i = threadIdx.x; i < HW; i += 256) s += px[i];
  __shared__ float red[256];
  red[threadIdx.x] = s; __syncthreads();
  for (int st = 128; st > 0; st >>= 1) {
    if (threadIdx.x < st) red[threadIdx.x] += red[threadIdx.x + st];
    __syncthreads();
  }
  if (threadIdx.x == 0) mean[bc] = red[0] * (1.0f / HW);
}

// ---------------- K2: GatherExcite MLP gate, folded into Wk ----------------
__global__ __launch_bounds__(256) void k_gate(const float* __restrict__ mean,
    const float* __restrict__ gw1, const float* __restrict__ gb1,
    const float* __restrict__ gw2, const float* __restrict__ gb2,
    const float* __restrict__ Wk, float* __restrict__ wkb) {
  int b = blockIdx.x;
  int t = threadIdx.x;                        // = channel c
  __shared__ float ms[CH];
  __shared__ float hid[RD];
  ms[t] = mean[b * CH + t];
  __syncthreads();
  if (t < RD) {
    float a = gb1[t];
    for (int c = 0; c < CH; ++c) a += gw1[t * CH + c] * ms[c];
    hid[t] = fmaxf(a, 0.f);
  }
  __syncthreads();
  float a = gb2[t];
  #pragma unroll
  for (int r = 0; r < RD; ++r) a += gw2[t * RD + r] * hid[r];
  float s = 1.f / (1.f + __expf(-a));         // sigmoid gate for channel t
  for (int kk = 0; kk < KC; ++kk)
    wkb[((size_t)b * KC + kk) * CH + t] = Wk[kk * CH + t] * s;
}

// ---------------- K3: fused 1x1 projections  ----------------
__global__ __launch_bounds__(256, 2) void k_proj(
    const float* __restrict__ x, const float* __restrict__ Wq,
    const float* __restrict__ wkb, const float* __restrict__ Wb1,
    const float* __restrict__ Wb2, const float* __restrict__ Wv,
    bf16* __restrict__ qt, bf16* __restrict__ kt,
    float* __restrict__ b1r, float* __restrict__ b2r, bf16* __restrict__ vt) {
  __shared__ __align__(16) float xs[CH * 36];
  const int blk  = blockIdx.x;
  const int half = blk & 1;
  const int nn   = (blk >> 1) & 127;
  const int b    = blk >> 8;
  const int n0   = nn * 32;
  const int t    = threadIdx.x;
  {
    const int j = t & 31, crow = t >> 5;
    const float* xb = x + ((size_t)b * CH) * HW + n0;
    #pragma unroll
    for (int i = 0; i < 32; ++i) {
      int c = crow + 8 * i;
      xs[c * 36 + j] = xb[(size_t)c * HW + j];
    }
  }
  __syncthreads();
  const int og = t >> 3;
  const int jg = t & 7;
  const float* wkb_b = wkb + (size_t)b * KC * CH;
  const float* wp[6];
  #pragma unroll
  for (int oo = 0; oo < 6; ++oo) {
    int o = half * 192 + og * 6 + oo;
    const float* w;
    if (o < 32)       w = Wq   + o * CH;
    else if (o < 64)  w = wkb_b + (o - 32) * CH;
    else if (o < 96)  w = Wb1  + (o - 64) * CH;
    else if (o < 128) w = Wb2  + (o - 96) * CH;
    else              w = Wv   + (o - 128) * CH;
    wp[oo] = w;
  }
  float acc[6][4];
  #pragma unroll
  for (int oo = 0; oo < 6; ++oo)
    #pragma unroll
    for (int jj = 0; jj < 4; ++jj) acc[oo][jj] = 0.f;
  for (int c0 = 0; c0 < CH; c0 += 4) {
    v4f xv[4];
    #pragma unroll
    for (int cc = 0; cc < 4; ++cc)
      xv[cc] = *(const v4f*)&xs[(c0 + cc) * 36 + jg * 4];
    #pragma unroll
    for (int oo = 0; oo < 6; ++oo) {
      v4f wv = *(const v4f*)(wp[oo] + c0);
      #pragma unroll
      for (int cc = 0; cc < 4; ++cc)
        #pragma unroll
        for (int jj = 0; jj < 4; ++jj)
          acc[oo][jj] += wv[cc] * xv[cc][jj];
    }
  }
  #pragma unroll
  for (int oo = 0; oo < 6; ++oo) {
    int o = half * 192 + og * 6 + oo;
    #pragma unroll
    for (int jj = 0; jj < 4; ++jj) {
      int n = n0 + jg * 4 + jj;
      size_t nb = (size_t)b * HW + n;
      float v = acc[oo][jj];
      if (o < 32)       qt[nb * KC + o] = (bf16)v;
      else if (o < 64)  kt[nb * KC + (o - 32)] = (bf16)v;
      else if (o < 96)  b1r[nb * KC + (o - 64)] = fmaxf(v, 0.f);
      else if (o < 128) b2r[nb * KC + (o - 96)] = fmaxf(v, 0.f);
      else              vt[((size_t)b * CH + (o - 128)) * VSTRIDE + n] = (bf16)v;
    }
  }
}

// ---------------- K3b: 1-D 3-tap pool of the bias factors (w_gb/9 folded into bs1) ----
__global__ __launch_bounds__(256) void k_pool(const float* __restrict__ b1r,
    const float* __restrict__ b2r, const float* __restrict__ wgb,
    bf16* __restrict__ bs1, bf16* __restrict__ bs2) {
  int i = blockIdx.x * 256 + threadIdx.x;
  int n = (i >> 5) & (HW - 1);
  float a = b1r[i], c = b2r[i];
  if (n > 0)      { a += b1r[i - KC]; c += b2r[i - KC]; }
  if (n < HW - 1) { a += b1r[i + KC]; c += b2r[i + KC]; }
  const float ws = wgb[0] * (1.f / 9.f);
  bs1[i] = (bf16)(a * ws);
  bs2[i] = (bf16)c;
}

// ---------------- K4: flash attention, swapped-QK + channel-split PV ----------------
// blk = rt*8 + os; rt = 64-row tile (b = rt>>6), os = key-split (512 keys, 8 steps of 64).
// 4 waves; QK: wave w computes P for rows [w*16,+16) (lane-local rows via swapped MFMA).
// PV: wave w computes ALL 64 rows x channels [w*64,+64); V B-frags direct from global.
__global__ __launch_bounds__(256, 3) void k_attn(
    const bf16* __restrict__ qtg, const bf16* __restrict__ ktg,
    const bf16* __restrict__ bs1g, const bf16* __restrict__ bs2g,
    const bf16* __restrict__ vtg,
    bf16* __restrict__ pacc, float* __restrict__ pl) {
  __shared__ __align__(16) bf16 kbuf[2][64][40];  // K tile dbuf, 80B rows
  __shared__ __align__(16) bf16 bbuf[2][64][40];  // B2 tile dbuf
  __shared__ __align__(16) bf16 plds[64][72];     // shared P [row][key], 144B rows
  const int blk = blockIdx.x;
  const int rt  = blk >> 3;                  // 0..127
  const int os  = blk & 7;
  const int b   = rt >> 6;
  const int row0 = (rt & 63) * 64;
  const int w    = threadIdx.x >> 6;
  const int lane = threadIdx.x & 63;
  const int cl = lane & 15;
  const int kh = lane >> 4;
  const int kb = os * 512;
  const v4f vzero = {0.f, 0.f, 0.f, 0.f};
  // Q/B1 as MFMA B-operand: lane supplies Q[row=w*16+cl][k=kh*8+j]
  const size_t qoff = ((size_t)(b * HW + row0 + w * 16 + cl)) * KC + kh * 8;
  const v8bf qf  = *(const v8bf*)(qtg + qoff);
  const v8bf b1f = *(const v8bf*)(bs1g + qoff);
  const bf16* kt = ktg + (size_t)b * HW * KC;
  const bf16* b2 = bs2g + (size_t)b * HW * KC;
  const bf16* vt = vtg + (size_t)b * CH * VSTRIDE;
  // staging roles: thread t stages K/B2 row t>>2, 8-elem slot (t&3)*8
  const int srow = threadIdx.x >> 2, sslot = (threadIdx.x & 3) * 8;

  // prologue: stage K/B2 for step 0
  *(v8bf*)&kbuf[0][srow][sslot] = *(const v8bf*)(kt + (size_t)(kb + srow) * KC + sslot);
  *(v8bf*)&bbuf[0][srow][sslot] = *(const v8bf*)(b2 + (size_t)(kb + srow) * KC + sslot);
  __syncthreads();

  v4f acc[16];                               // [rg][cg]
  #pragma unroll
  for (int f = 0; f < 16; ++f) acc[f] = vzero;
  float psum = 0.f;

  for (int s = 0; s < 8; ++s) {
    const int m0 = kb + s * 64;
    const int pb = s & 1;
    // V B-frags direct from global: lane reads V^T[ch=w*64+cg*16+cl][keys m0+ks*32+kh*8..]
    v8bf vb[8];
    #pragma unroll
    for (int cg = 0; cg < 4; ++cg)
      #pragma unroll
      for (int ks = 0; ks < 2; ++ks)
        vb[cg * 2 + ks] = *(const v8bf*)(vt +
            (size_t)(w * 64 + cg * 16 + cl) * VSTRIDE + m0 + ks * 32 + kh * 8);
    // prefetch next K/B2
    v8bf kr, br;
    if (s < 7) {
      kr = *(const v8bf*)(kt + (size_t)(m0 + 64 + srow) * KC + sslot);
      br = *(const v8bf*)(b2 + (size_t)(m0 + 64 + srow) * KC + sslot);
    }
    // swapped QK: sim = mfma(K,Q) -> C[key][qrow]; lane owns 16 keys of ITS row (w*16+cl)
    #pragma unroll
    for (int cb = 0; cb < 4; ++cb) {
      v8bf kf  = *(const v8bf*)&kbuf[pb][cb * 16 + cl][kh * 8];
      v8bf b2f = *(const v8bf*)&bbuf[pb][cb * 16 + cl][kh * 8];
      v4f sim = __builtin_amdgcn_mfma_f32_16x16x32_bf16(kf,  qf,  vzero, 0, 0, 0);
      v4f bia = __builtin_amdgcn_mfma_f32_16x16x32_bf16(b2f, b1f, vzero, 0, 0, 0);
      v4bf pk;
      #pragma unroll
      for (int r = 0; r < 4; ++r) {
        float bm = 1.f / (1.f + __expf(-bia[r]));   // sigmoid(w_gb*pooled/9), scale pre-folded
        float pv = __expf(sim[r] * bm);             // bounded scores: no max subtraction
        psum += pv;
        pk[r] = (bf16)pv;
      }
      // keys cb*16+kh*4..+4 of row w*16+cl -> contiguous 8B write
      *(v4bf*)&plds[w * 16 + cl][cb * 16 + kh * 4] = pk;
    }
    // stage next K/B2 (vmcnt wait auto-inserted)
    if (s < 7) {
      *(v8bf*)&kbuf[pb ^ 1][srow][sslot] = kr;
      *(v8bf*)&bbuf[pb ^ 1][srow][sslot] = br;
    }
    __syncthreads();                         // P visible to all waves
    // PV: A-frags = P rows (all 4 row-groups), B-frags = vb (direct-global)
    v8bf pa[8];
    #pragma unroll
    for (int rg = 0; rg < 4; ++rg)
      #pragma unroll
      for (int ks = 0; ks < 2; ++ks)
        pa[rg * 2 + ks] = *(const v8bf*)&plds[rg * 16 + cl][ks * 32 + kh * 8];
    #pragma unroll
    for (int rg = 0; rg < 4; ++rg)
      #pragma unroll
      for (int cg = 0; cg < 4; ++cg) {
        acc[rg * 4 + cg] = __builtin_amdgcn_mfma_f32_16x16x32_bf16(
            pa[rg * 2 + 0], vb[cg * 2 + 0], acc[rg * 4 + cg], 0, 0, 0);
        acc[rg * 4 + cg] = __builtin_amdgcn_mfma_f32_16x16x32_bf16(
            pa[rg * 2 + 1], vb[cg * 2 + 1], acc[rg * 4 + cg], 0, 0, 0);
      }
    __syncthreads();                         // plds consumed; safe to overwrite next step
  }

  // ---- epilogue ----
  // row-sum: lane (cl,kh) holds partial over its kh key-quarter; reduce across kh
  {
    float s2 = psum;
    s2 += __shfl_xor(s2, 16);
    s2 += __shfl_xor(s2, 32);
    if (kh == 0) pl[blk * 64 + w * 16 + cl] = s2;
  }
  // acc[rg][cg]: row rg*16+kh*4+r, ch w*64+cg*16+cl -> transpose via plds per rg round
  bf16 (*trans)[288] = (bf16 (*)[288])plds;  // 16 x 288 x 2B = 9216 B (fits plds exactly)
  bf16* po = pacc + (size_t)blk * 64 * CH;
  for (int rg = 0; rg < 4; ++rg) {
    __syncthreads();
    #pragma unroll
    for (int cg = 0; cg < 4; ++cg)
      #pragma unroll
      for (int r = 0; r < 4; ++r)
        trans[kh * 4 + r][w * 64 + cg * 16 + cl] = (bf16)acc[rg * 4 + cg][r];
    __syncthreads();
    #pragma unroll
    for (int it = 0; it < 2; ++it) {
      int idx = threadIdx.x + it * 256;
      int row = idx >> 5, ch = (idx & 31) * 8;
      *(v8bf*)&po[(size_t)(rg * 16 + row) * CH + ch] = *(const v8bf*)&trans[row][ch];
    }
  }
}

// ---------------- K4b: split-K combine (plain sum + divide) ----------------
__global__ __launch_bounds__(256) void k_combine(const bf16* __restrict__ pacc,
    const float* __restrict__ pl, bf16* __restrict__ ctx) {
  const int r = blockIdx.x * 4 + (threadIdx.x >> 6);   // global row 0..8191
  const int lane = threadIdx.x & 63;
  const int rt = r >> 6;
  const int rl = r & 63;
  const int base = rt * 8;
  float den = 0.f;
  #pragma unroll
  for (int s = 0; s < 8; ++s) den += pl[(base + s) * 64 + rl];
  const float inv = 1.f / den;
  #pragma unroll
  for (int c0 = 0; c0 < CH; c0 += 64) {
    int c = c0 + lane;
    float a = 0.f;
    #pragma unroll
    for (int s = 0; s < 8; ++s)
      a += (float)pacc[((size_t)(base + s) * 64 + rl) * CH + c];
    ctx[(size_t)r * CH + c] = (bf16)(a * inv);
  }
}

// ---------------- K5: output 1x1 conv + BN + ReLU + residual ----------------
__global__ __launch_bounds__(256, 2) void k_out(
    const bf16* __restrict__ ctx, const float* __restrict__ Wo,
    const float* __restrict__ bns, const float* __restrict__ bnb,
    const float* __restrict__ bnm, const float* __restrict__ bnv,
    const float* __restrict__ gamma, const float* __restrict__ x,
    float* __restrict__ out) {
  __shared__ __align__(16) float cs[CH * 36];
  const int blk  = blockIdx.x;
  const int half = blk & 1;
  const int nn   = (blk >> 1) & 127;
  const int b    = blk >> 8;
  const int n0   = nn * 32;
  const int t    = threadIdx.x;
  for (int i = t; i < 32 * 256; i += 256) {
    int j = i >> 8, c = i & 255;
    cs[c * 36 + j] = (float)ctx[((size_t)b * HW + n0 + j) * CH + c];
  }
  __syncthreads();
  const int og = t >> 3, jg = t & 7;
  float acc[4][4];
  #pragma unroll
  for (int oo = 0; oo < 4; ++oo)
    #pragma unroll
    for (int jj = 0; jj < 4; ++jj) acc[oo][jj] = 0.f;
  const int o0 = half * 128 + og * 4;
  for (int c0 = 0; c0 < CH; c0 += 4) {
    v4f xv[4];
    #pragma unroll
    for (int cc = 0; cc < 4; ++cc)
      xv[cc] = *(const v4f*)&cs[(c0 + cc) * 36 + jg * 4];
    #pragma unroll
    for (int oo = 0; oo < 4; ++oo) {
      v4f wv = *(const v4f*)&Wo[(o0 + oo) * CH + c0];
      #pragma unroll
      for (int cc = 0; cc < 4; ++cc)
        #pragma unroll
        for (int jj = 0; jj < 4; ++jj)
          acc[oo][jj] += wv[cc] * xv[cc][jj];
    }
  }
  const float g = gamma[0];
  #pragma unroll
  for (int oo = 0; oo < 4; ++oo) {
    int o = o0 + oo;
    float isc = bns[o] / sqrtf(bnv[o] + BNEPS);
    float mu = bnm[o], bb = bnb[o];
    #pragma unroll
    for (int jj = 0; jj < 4; ++jj) {
      int n = n0 + jg * 4 + jj;
      float v = (acc[oo][jj] - mu) * isc + bb;
      v = fmaxf(v, 0.f);
      size_t oi = ((size_t)b * CH + o) * HW + n;
      out[oi] = g * v + x[oi];
    }
  }
}

// ---------------- launch ----------------
extern "C" void kernel_launch(void* const* d_in, const int* in_sizes, int n_in,
                              void* d_out, int out_size, void* d_ws, size_t ws_size,
                              hipStream_t stream) {
  const float* x    = (const float*)d_in[0];
  const float* Wq   = (const float*)d_in[1];
  const float* Wk   = (const float*)d_in[2];
  const float* Wv   = (const float*)d_in[3];
  const float* Wb1  = (const float*)d_in[4];
  const float* Wb2  = (const float*)d_in[5];
  const float* wgb  = (const float*)d_in[6];
  const float* gw1  = (const float*)d_in[7];
  const float* gb1  = (const float*)d_in[8];
  const float* gw2  = (const float*)d_in[9];
  const float* gb2  = (const float*)d_in[10];
  const float* Wo   = (const float*)d_in[11];
  const float* bns  = (const float*)d_in[12];
  const float* bnb  = (const float*)d_in[13];
  const float* bnm  = (const float*)d_in[14];
  const float* bnv  = (const float*)d_in[15];
  const float* gam  = (const float*)d_in[16];

  char* ws = (char*)d_ws;
  float* mean = (float*)(ws + OFF_MEAN);
  float* wkb  = (float*)(ws + OFF_WKB);
  bf16* qt    = (bf16*)(ws + OFF_QT);
  bf16* kt    = (bf16*)(ws + OFF_KT);
  bf16* bs1   = (bf16*)(ws + OFF_BS1);
  bf16* bs2   = (bf16*)(ws + OFF_BS2);
  bf16* vt    = (bf16*)(ws + OFF_VT);
  float* b1r  = (float*)(ws + OFF_B1R);
  float* b2r  = (float*)(ws + OFF_B2R);
  bf16* ctx   = (bf16*)(ws + OFF_CTX);
  bf16* pacc  = (bf16*)(ws + OFF_PACC);
  float* plv  = (float*)(ws + OFF_PL);
  float* out  = (float*)d_out;

  hipLaunchKernelGGL(k_mean,    dim3(NB * CH),        dim3(256), 0, stream, x, mean);
  hipLaunchKernelGGL(k_gate,    dim3(NB),             dim3(256), 0, stream, mean, gw1, gb1, gw2, gb2, Wk, wkb);
  hipLaunchKernelGGL(k_proj,    dim3(NB * 128 * 2),   dim3(256), 0, stream, x, Wq, wkb, Wb1, Wb2, Wv, qt, kt, b1r, b2r, vt);
  hipLaunchKernelGGL(k_pool,    dim3(NB * HW * KC / 256), dim3(256), 0, stream, b1r, b2r, wgb, bs1, bs2);
  hipLaunchKernelGGL(k_attn,    dim3(1024),           dim3(256), 0, stream, qt, kt, bs1, bs2, vt, pacc, plv);
  hipLaunchKernelGGL(k_combine, dim3(NB * HW / 4),    dim3(256), 0, stream, pacc, plv, ctx);
  hipLaunchKernelGGL(k_out,     dim3(NB * 128 * 2),   dim3(256), 0, stream, ctx, Wo, bns, bnb, bnm, bnv, gam, x, out);
}

// Round 7
// 110.757 us; speedup vs baseline: 1.1606x; 1.1606x over previous
//
#include <hip/hip_runtime.h>
#include <hip/hip_bf16.h>

typedef __bf16 bf16;
typedef __bf16 v8bf __attribute__((ext_vector_type(8)));
typedef __bf16 v4bf __attribute__((ext_vector_type(4)));
typedef float v4f __attribute__((ext_vector_type(4)));

#define HW 4096
#define CH 256
#define KC 32
#define RD 16
#define NB 2
#define BNEPS 1e-5f
#define VSTRIDE 4224

// ---------------- workspace byte offsets (~28.5 MiB) ----------------
#define OFF_MEAN   0u          // f32 [2][256]
#define OFF_WKB    4096u       // f32 [2][32][256] gate-folded Wk
#define OFF_QT     69632u      // bf16 [2][4096][32]
#define OFF_KT     593920u     // bf16 [2][4096][32]
#define OFF_BS1    1118208u    // bf16 [2][4096][32] pooled b1 (pre-scaled by w_gb/9)
#define OFF_BS2    1642496u    // bf16 [2][4096][32] pooled b2
#define OFF_VT     2166784u    // bf16 [2][256][VSTRIDE] V transposed (padded rows)
#define OFF_B1R    6492160u    // bf16 [2][4096][32] raw relu(Wb1 x)
#define OFF_B2R    7540736u    // bf16 [2][4096][32]
#define OFF_CTX    8589312u    // bf16 [2][4096][256]
#define OFF_PACC   12783616u   // bf16 [512][64][256] split-K partial ctx
#define OFF_PL     29560832u   // f32 [512*64] partial softmax denominators
#define OFF_WOBF   29691904u   // bf16 [256][256] Wo converted

// ---------------- K1: per-(b,c) spatial mean ----------------
__global__ __launch_bounds__(256) void k_mean(const float* __restrict__ x,
                                              float* __restrict__ mean) {
  int bc = blockIdx.x;                       // 0..511
  const float* px = x + (size_t)bc * HW;
  float s = 0.f;
  for (int i = threadIdx.x; i < HW; i += 256) s += px[i];
  __shared__ float red[256];
  red[threadIdx.x] = s; __syncthreads();
  for (int st = 128; st > 0; st >>= 1) {
    if (threadIdx.x < st) red[threadIdx.x] += red[threadIdx.x + st];
    __syncthreads();
  }
  if (threadIdx.x == 0) mean[bc] = red[0] * (1.0f / HW);
}

// ---------------- K2: GatherExcite gate folded into Wk; blocks>=2 convert Wo->bf16 ----
__global__ __launch_bounds__(256) void k_gate(const float* __restrict__ mean,
    const float* __restrict__ gw1, const float* __restrict__ gb1,
    const float* __restrict__ gw2, const float* __restrict__ gb2,
    const float* __restrict__ Wk, float* __restrict__ wkb,
    const float* __restrict__ Wo, bf16* __restrict__ wo_bf) {
  if (blockIdx.x >= 2) {                     // Wo f32 -> bf16 (65536 elems / 256 blocks)
    int i = (blockIdx.x - 2) * 256 + threadIdx.x;
    wo_bf[i] = (bf16)Wo[i];
    return;
  }
  int b = blockIdx.x;
  int t = threadIdx.x;                        // = channel c
  __shared__ float ms[CH];
  __shared__ float hid[RD];
  ms[t] = mean[b * CH + t];
  __syncthreads();
  if (t < RD) {
    float a = gb1[t];
    for (int c = 0; c < CH; ++c) a += gw1[t * CH + c] * ms[c];
    hid[t] = fmaxf(a, 0.f);
  }
  __syncthreads();
  float a = gb2[t];
  #pragma unroll
  for (int r = 0; r < RD; ++r) a += gw2[t * RD + r] * hid[r];
  float s = 1.f / (1.f + __expf(-a));         // sigmoid gate for channel t
  for (int kk = 0; kk < KC; ++kk)
    wkb[((size_t)b * KC + kk) * CH + t] = Wk[kk * CH + t] * s;
}

// ---------------- K3: fused 1x1 projections  ----------------
__global__ __launch_bounds__(256, 2) void k_proj(
    const float* __restrict__ x, const float* __restrict__ Wq,
    const float* __restrict__ wkb, const float* __restrict__ Wb1,
    const float* __restrict__ Wb2, const float* __restrict__ Wv,
    bf16* __restrict__ qt, bf16* __restrict__ kt,
    bf16* __restrict__ b1r, bf16* __restrict__ b2r, bf16* __restrict__ vt) {
  __shared__ __align__(16) float xs[CH * 36];
  const int blk  = blockIdx.x;
  const int half = blk & 1;
  const int nn   = (blk >> 1) & 127;
  const int b    = blk >> 8;
  const int n0   = nn * 32;
  const int t    = threadIdx.x;
  {
    const int j = t & 31, crow = t >> 5;
    const float* xb = x + ((size_t)b * CH) * HW + n0;
    #pragma unroll
    for (int i = 0; i < 32; ++i) {
      int c = crow + 8 * i;
      xs[c * 36 + j] = xb[(size_t)c * HW + j];
    }
  }
  __syncthreads();
  const int og = t >> 3;
  const int jg = t & 7;
  const float* wkb_b = wkb + (size_t)b * KC * CH;
  const float* wp[6];
  #pragma unroll
  for (int oo = 0; oo < 6; ++oo) {
    int o = half * 192 + og * 6 + oo;
    const float* w;
    if (o < 32)       w = Wq   + o * CH;
    else if (o < 64)  w = wkb_b + (o - 32) * CH;
    else if (o < 96)  w = Wb1  + (o - 64) * CH;
    else if (o < 128) w = Wb2  + (o - 96) * CH;
    else              w = Wv   + (o - 128) * CH;
    wp[oo] = w;
  }
  float acc[6][4];
  #pragma unroll
  for (int oo = 0; oo < 6; ++oo)
    #pragma unroll
    for (int jj = 0; jj < 4; ++jj) acc[oo][jj] = 0.f;
  for (int c0 = 0; c0 < CH; c0 += 4) {
    v4f xv[4];
    #pragma unroll
    for (int cc = 0; cc < 4; ++cc)
      xv[cc] = *(const v4f*)&xs[(c0 + cc) * 36 + jg * 4];
    #pragma unroll
    for (int oo = 0; oo < 6; ++oo) {
      v4f wv = *(const v4f*)(wp[oo] + c0);
      #pragma unroll
      for (int cc = 0; cc < 4; ++cc)
        #pragma unroll
        for (int jj = 0; jj < 4; ++jj)
          acc[oo][jj] += wv[cc] * xv[cc][jj];
    }
  }
  #pragma unroll
  for (int oo = 0; oo < 6; ++oo) {
    int o = half * 192 + og * 6 + oo;
    #pragma unroll
    for (int jj = 0; jj < 4; ++jj) {
      int n = n0 + jg * 4 + jj;
      size_t nb = (size_t)b * HW + n;
      float v = acc[oo][jj];
      if (o < 32)       qt[nb * KC + o] = (bf16)v;
      else if (o < 64)  kt[nb * KC + (o - 32)] = (bf16)v;
      else if (o < 96)  b1r[nb * KC + (o - 64)] = (bf16)fmaxf(v, 0.f);
      else if (o < 128) b2r[nb * KC + (o - 96)] = (bf16)fmaxf(v, 0.f);
      else              vt[((size_t)b * CH + (o - 128)) * VSTRIDE + n] = (bf16)v;
    }
  }
}

// ---------------- K3b: 1-D 3-tap pool of the bias factors (w_gb/9 folded into bs1) ----
__global__ __launch_bounds__(256) void k_pool(const bf16* __restrict__ b1r,
    const bf16* __restrict__ b2r, const float* __restrict__ wgb,
    bf16* __restrict__ bs1, bf16* __restrict__ bs2) {
  int i = blockIdx.x * 256 + threadIdx.x;
  int n = (i >> 5) & (HW - 1);
  float a = (float)b1r[i], c = (float)b2r[i];
  if (n > 0)      { a += (float)b1r[i - KC]; c += (float)b2r[i - KC]; }
  if (n < HW - 1) { a += (float)b1r[i + KC]; c += (float)b2r[i + KC]; }
  const float ws = wgb[0] * (1.f / 9.f);
  bs1[i] = (bf16)(a * ws);
  bs2[i] = (bf16)c;
}

// ---------------- K4: flash attention, LDS staging + XOR-swizzled V buffer ----------
// blk = rt*4 + os; rt = 64-row tile (b = rt>>6), os = key-split (1024 keys).
// 4 waves; wave w owns rows [w*16, w*16+16). 16 steps of 64 keys.
__global__ __launch_bounds__(256, 2) void k_attn(
    const bf16* __restrict__ qtg, const bf16* __restrict__ ktg,
    const bf16* __restrict__ bs1g, const bf16* __restrict__ bs2g,
    const bf16* __restrict__ vtg,
    bf16* __restrict__ pacc, float* __restrict__ pl) {
  __shared__ __align__(16) bf16 vbuf[256][64];    // V tile, 128B rows, XOR slot swizzle
  __shared__ __align__(16) bf16 kbuf[2][64][40];  // K tile dbuf, 80B rows (2-way max)
  __shared__ __align__(16) bf16 bbuf[2][64][40];  // B2 tile dbuf
  __shared__ __align__(16) bf16 plds[4][16][72];  // per-wave P relayout
  const int blk = blockIdx.x;
  const int rt  = blk >> 2;
  const int os  = blk & 3;
  const int b   = rt >> 6;
  const int row0 = (rt & 63) * 64;
  const int w    = threadIdx.x >> 6;
  const int lane = threadIdx.x & 63;
  const int cl = lane & 15;
  const int kh = lane >> 4;
  const int kb = os * 1024;
  const v4f vzero = {0.f, 0.f, 0.f, 0.f};
  const size_t qoff = ((size_t)(b * HW + row0 + w * 16 + cl)) * KC + kh * 8;
  const v8bf qf  = *(const v8bf*)(qtg + qoff);
  const v8bf b1f = *(const v8bf*)(bs1g + qoff);
  const bf16* kt = ktg + (size_t)b * HW * KC;
  const bf16* b2 = bs2g + (size_t)b * HW * KC;
  const bf16* vt = vtg + (size_t)b * CH * VSTRIDE;
  // staging lane roles
  const int krow = w * 16 + (lane >> 2), kslot = (lane & 3) * 8;   // K/B2: 16 rows/wave
  const int vch   = w * 64 + (lane >> 3);                          // V: 64 ch/wave (+i*8)
  const int vslog = lane & 7;                                      // logical 16B slot
  const int vwr   = (vslog ^ (lane >> 3)) * 8;                     // physical (row&7 = lane>>3)
  // swizzled read offsets (row&7 = cl&7, constant per lane)
  const int x7 = cl & 7;
  const int ro0 = (kh ^ x7) * 8;
  const int ro1 = ((kh + 4) ^ x7) * 8;

  // prologue: stage K/B2 for step 0
  {
    v8bf kr = *(const v8bf*)(kt + (size_t)(kb + krow) * KC + kslot);
    v8bf br = *(const v8bf*)(b2 + (size_t)(kb + krow) * KC + kslot);
    *(v8bf*)&kbuf[0][krow][kslot] = kr;
    *(v8bf*)&bbuf[0][krow][kslot] = br;
  }
  __syncthreads();

  v4f acc[16];
  #pragma unroll
  for (int f = 0; f < 16; ++f) acc[f] = vzero;
  float psum[4] = {0.f, 0.f, 0.f, 0.f};

  for (int s = 0; s < 16; ++s) {
    const int m0 = kb + s * 64;
    const int pb = s & 1;
    // issue V tile loads (consumed after QK)
    v8bf vr[8];
    #pragma unroll
    for (int i = 0; i < 8; ++i)
      vr[i] = *(const v8bf*)(vt + (size_t)(vch + i * 8) * VSTRIDE + m0 + vslog * 8);
    // issue next-step K/B2 loads
    v8bf kr, br;
    if (s + 1 < 16) {
      kr = *(const v8bf*)(kt + (size_t)(m0 + 64 + krow) * KC + kslot);
      br = *(const v8bf*)(b2 + (size_t)(m0 + 64 + krow) * KC + kslot);
    }
    // QK + bias from LDS
    v4f sim[4], bia[4];
    #pragma unroll
    for (int cb = 0; cb < 4; ++cb) {
      v8bf kf  = *(const v8bf*)&kbuf[pb][cb * 16 + cl][kh * 8];
      v8bf b2f = *(const v8bf*)&bbuf[pb][cb * 16 + cl][kh * 8];
      sim[cb] = __builtin_amdgcn_mfma_f32_16x16x32_bf16(qf,  kf,  vzero, 0, 0, 0);
      bia[cb] = __builtin_amdgcn_mfma_f32_16x16x32_bf16(b1f, b2f, vzero, 0, 0, 0);
    }
    // bounded scores: exp without max subtraction (e^M cancels in p/sum)
    float p[4][4];
    #pragma unroll
    for (int cb = 0; cb < 4; ++cb)
      #pragma unroll
      for (int r = 0; r < 4; ++r) {
        float bm = 1.f / (1.f + __expf(-bia[cb][r]));   // w_gb/9 pre-folded into bs1
        float pv = __expf(sim[cb][r] * bm);
        p[cb][r] = pv;
        psum[r] += pv;
      }
    // P relayout via per-wave LDS
    #pragma unroll
    for (int cb = 0; cb < 4; ++cb)
      #pragma unroll
      for (int r = 0; r < 4; ++r)
        plds[w][kh * 4 + r][cb * 16 + cl] = (bf16)p[cb][r];
    asm volatile("s_waitcnt lgkmcnt(0)" ::: "memory");
    __builtin_amdgcn_sched_barrier(0);
    const v8bf pa0 = *(const v8bf*)&plds[w][cl][kh * 8];
    const v8bf pa1 = *(const v8bf*)&plds[w][cl][32 + kh * 8];
    // stage V tile (swizzled write; vmcnt for vr auto-inserted; K-next stays in flight)
    #pragma unroll
    for (int i = 0; i < 8; ++i)
      *(v8bf*)&vbuf[vch + i * 8][vwr] = vr[i];
    __syncthreads();
    // PV from LDS (swizzled read: each 16-lane quarter spans all 32 banks, 2-way)
    #pragma unroll
    for (int f = 0; f < 16; ++f) {
      v8bf v0 = *(const v8bf*)&vbuf[f * 16 + cl][ro0];
      v8bf v1 = *(const v8bf*)&vbuf[f * 16 + cl][ro1];
      acc[f] = __builtin_amdgcn_mfma_f32_16x16x32_bf16(pa0, v0, acc[f], 0, 0, 0);
      acc[f] = __builtin_amdgcn_mfma_f32_16x16x32_bf16(pa1, v1, acc[f], 0, 0, 0);
    }
    // stage next K/B2
    if (s + 1 < 16) {
      *(v8bf*)&kbuf[pb ^ 1][krow][kslot] = kr;
      *(v8bf*)&bbuf[pb ^ 1][krow][kslot] = br;
    }
    __syncthreads();   // vbuf consumed + next K ready
  }

  // ---- epilogue: per-wave (waves own disjoint rows; no cross-wave reduce) ----
  #pragma unroll
  for (int r = 0; r < 4; ++r) {
    float s = psum[r];
    s += __shfl_xor(s, 1);
    s += __shfl_xor(s, 2);
    s += __shfl_xor(s, 4);
    s += __shfl_xor(s, 8);
    if (cl == 0) pl[blk * 64 + w * 16 + kh * 4 + r] = s;
  }
  // acc store via per-wave LDS transpose for coalescing
  bf16* po = pacc + (size_t)blk * 64 * CH;
  for (int c4 = 0; c4 < 4; ++c4) {
    #pragma unroll
    for (int ff = 0; ff < 4; ++ff)
      #pragma unroll
      for (int r = 0; r < 4; ++r)
        plds[w][kh * 4 + r][ff * 16 + cl] = (bf16)acc[c4 * 4 + ff][r];
    asm volatile("s_waitcnt lgkmcnt(0)" ::: "memory");
    __builtin_amdgcn_sched_barrier(0);
    #pragma unroll
    for (int it = 0; it < 2; ++it) {
      int row = lane >> 2, chunk = it * 4 + (lane & 3);
      v8bf d = *(const v8bf*)&plds[w][row][chunk * 8];
      *(v8bf*)&po[(size_t)(w * 16 + row) * CH + c4 * 64 + chunk * 8] = d;
    }
  }
}

// ---------------- K4b: split-K combine (plain sum + divide) ----------------
__global__ __launch_bounds__(256) void k_combine(const bf16* __restrict__ pacc,
    const float* __restrict__ pl, bf16* __restrict__ ctx) {
  const int r = blockIdx.x * 4 + (threadIdx.x >> 6);   // global row 0..8191
  const int lane = threadIdx.x & 63;
  const int rt = r >> 6;
  const int rl = r & 63;
  const int base = rt * 4;
  float den = 0.f;
  #pragma unroll
  for (int s = 0; s < 4; ++s) den += pl[(base + s) * 64 + rl];
  const float inv = 1.f / den;
  #pragma unroll
  for (int c0 = 0; c0 < CH; c0 += 64) {
    int c = c0 + lane;
    float a = 0.f;
    #pragma unroll
    for (int s = 0; s < 4; ++s)
      a += (float)pacc[((size_t)(base + s) * 64 + rl) * CH + c];
    ctx[(size_t)r * CH + c] = (bf16)(a * inv);
  }
}

// ---------------- K5: output 1x1 conv (MFMA) + BN + ReLU + residual ----------------
// 512 blocks x 16 rows; 4 waves, wave w -> cout [w*64, +64)
__global__ __launch_bounds__(256) void k_out(
    const bf16* __restrict__ ctx, const bf16* __restrict__ wo,
    const float* __restrict__ bns, const float* __restrict__ bnb,
    const float* __restrict__ bnm, const float* __restrict__ bnv,
    const float* __restrict__ gamma, const float* __restrict__ x,
    float* __restrict__ out) {
  const int blk = blockIdx.x;
  const int n0g = blk * 16;                 // global row
  const int b   = n0g >> 12;
  const int n0  = n0g & (HW - 1);
  const int t = threadIdx.x;
  const int w = t >> 6, lane = t & 63, cl = lane & 15, kh = lane >> 4;
  const v4f vzero = {0.f, 0.f, 0.f, 0.f};
  // A-frags: ctx rows n0g+cl, cin slices
  v8bf a[8];
  #pragma unroll
  for (int kk = 0; kk < 8; ++kk)
    a[kk] = *(const v8bf*)(ctx + (size_t)(n0g + cl) * CH + kk * 32 + kh * 8);
  v4f acc[4] = {vzero, vzero, vzero, vzero};
  #pragma unroll
  for (int kk = 0; kk < 8; ++kk)
    #pragma unroll
    for (int cg = 0; cg < 4; ++cg) {
      v8bf bfr = *(const v8bf*)(wo + (size_t)(w * 64 + cg * 16 + cl) * CH + kk * 32 + kh * 8);
      acc[cg] = __builtin_amdgcn_mfma_f32_16x16x32_bf16(a[kk], bfr, acc[cg], 0, 0, 0);
    }
  const float g = gamma[0];
  #pragma unroll
  for (int cg = 0; cg < 4; ++cg) {
    int o = w * 64 + cg * 16 + cl;
    float isc = bns[o] / sqrtf(bnv[o] + BNEPS);
    float mu = bnm[o], bb = bnb[o];
    size_t oi = ((size_t)b * CH + o) * HW + n0 + kh * 4;
    v4f xv = *(const v4f*)&x[oi];
    v4f ov;
    #pragma unroll
    for (int r = 0; r < 4; ++r) {
      float v = (acc[cg][r] - mu) * isc + bb;
      v = fmaxf(v, 0.f);
      ov[r] = g * v + xv[r];
    }
    *(v4f*)&out[oi] = ov;
  }
}

// ---------------- launch ----------------
extern "C" void kernel_launch(void* const* d_in, const int* in_sizes, int n_in,
                              void* d_out, int out_size, void* d_ws, size_t ws_size,
                              hipStream_t stream) {
  const float* x    = (const float*)d_in[0];
  const float* Wq   = (const float*)d_in[1];
  const float* Wk   = (const float*)d_in[2];
  const float* Wv   = (const float*)d_in[3];
  const float* Wb1  = (const float*)d_in[4];
  const float* Wb2  = (const float*)d_in[5];
  const float* wgb  = (const float*)d_in[6];
  const float* gw1  = (const float*)d_in[7];
  const float* gb1  = (const float*)d_in[8];
  const float* gw2  = (const float*)d_in[9];
  const float* gb2  = (const float*)d_in[10];
  const float* Wo   = (const float*)d_in[11];
  const float* bns  = (const float*)d_in[12];
  const float* bnb  = (const float*)d_in[13];
  const float* bnm  = (const float*)d_in[14];
  const float* bnv  = (const float*)d_in[15];
  const float* gam  = (const float*)d_in[16];

  char* ws = (char*)d_ws;
  float* mean = (float*)(ws + OFF_MEAN);
  float* wkb  = (float*)(ws + OFF_WKB);
  bf16* qt    = (bf16*)(ws + OFF_QT);
  bf16* kt    = (bf16*)(ws + OFF_KT);
  bf16* bs1   = (bf16*)(ws + OFF_BS1);
  bf16* bs2   = (bf16*)(ws + OFF_BS2);
  bf16* vt    = (bf16*)(ws + OFF_VT);
  bf16* b1r   = (bf16*)(ws + OFF_B1R);
  bf16* b2r   = (bf16*)(ws + OFF_B2R);
  bf16* ctx   = (bf16*)(ws + OFF_CTX);
  bf16* pacc  = (bf16*)(ws + OFF_PACC);
  float* plv  = (float*)(ws + OFF_PL);
  bf16* wobf  = (bf16*)(ws + OFF_WOBF);
  float* out  = (float*)d_out;

  hipLaunchKernelGGL(k_mean,    dim3(NB * CH),        dim3(256), 0, stream, x, mean);
  hipLaunchKernelGGL(k_gate,    dim3(2 + 256),        dim3(256), 0, stream, mean, gw1, gb1, gw2, gb2, Wk, wkb, Wo, wobf);
  hipLaunchKernelGGL(k_proj,    dim3(NB * 128 * 2),   dim3(256), 0, stream, x, Wq, wkb, Wb1, Wb2, Wv, qt, kt, b1r, b2r, vt);
  hipLaunchKernelGGL(k_pool,    dim3(NB * HW * KC / 256), dim3(256), 0, stream, b1r, b2r, wgb, bs1, bs2);
  hipLaunchKernelGGL(k_attn,    dim3(512),            dim3(256), 0, stream, qt, kt, bs1, bs2, vt, pacc, plv);
  hipLaunchKernelGGL(k_combine, dim3(NB * HW / 4),    dim3(256), 0, stream, pacc, plv, ctx);
  hipLaunchKernelGGL(k_out,     dim3(512),            dim3(256), 0, stream, ctx, wobf, bns, bnb, bnm, bnv, gam, x, out);
}

// Round 8
// 106.176 us; speedup vs baseline: 1.2107x; 1.0431x over previous
//
#include <hip/hip_runtime.h>
#include <hip/hip_bf16.h>

typedef __bf16 bf16;
typedef __bf16 v8bf __attribute__((ext_vector_type(8)));
typedef __bf16 v4bf __attribute__((ext_vector_type(4)));
typedef float v4f __attribute__((ext_vector_type(4)));

#define HW 4096
#define CH 256
#define KC 32
#define RD 16
#define NB 2
#define BNEPS 1e-5f
#define VSTRIDE 4224
#define LOG2E 1.4426950408889634f

__device__ __forceinline__ float fexp2(float x) {
#if __has_builtin(__builtin_amdgcn_exp2f)
  return __builtin_amdgcn_exp2f(x);
#else
  return exp2f(x);
#endif
}
__device__ __forceinline__ float frcp(float x) {
#if __has_builtin(__builtin_amdgcn_rcpf)
  return __builtin_amdgcn_rcpf(x);
#else
  return 1.f / x;
#endif
}

// ---------------- workspace byte offsets (~46.7 MiB) ----------------
#define OFF_MEAN   0u          // f32 [2][256]
#define OFF_WKB    4096u       // f32 [2][32][256] gate-folded Wk
#define OFF_QT     69632u      // bf16 [2][4096][32]  (pre-scaled by log2e)
#define OFF_KT     593920u     // bf16 [2][4096][32]
#define OFF_BS1    1118208u    // bf16 [2][4096][32] pooled b1 (scaled by -log2e*w_gb/9)
#define OFF_BS2    1642496u    // bf16 [2][4096][32] pooled b2
#define OFF_VT     2166784u    // bf16 [2][256][VSTRIDE] V transposed (padded rows)
#define OFF_B1R    6492160u    // bf16 [2][4096][32] raw relu(Wb1 x)
#define OFF_B2R    7540736u    // bf16 [2][4096][32]
#define OFF_CTX    8589312u    // bf16 [2][4096][256]
#define OFF_PACC   12783616u   // bf16 [1024][64][256] split-K partial ctx
#define OFF_PL     46338048u   // f32 [1024*64] partial softmax denominators
#define OFF_WOBF   46600192u   // bf16 [256][256] Wo converted

// ---------------- K1: per-(b,c) spatial mean ----------------
__global__ __launch_bounds__(256) void k_mean(const float* __restrict__ x,
                                              float* __restrict__ mean) {
  int bc = blockIdx.x;                       // 0..511
  const float* px = x + (size_t)bc * HW;
  float s = 0.f;
  for (int i = threadIdx.x; i < HW; i += 256) s += px[i];
  __shared__ float red[256];
  red[threadIdx.x] = s; __syncthreads();
  for (int st = 128; st > 0; st >>= 1) {
    if (threadIdx.x < st) red[threadIdx.x] += red[threadIdx.x + st];
    __syncthreads();
  }
  if (threadIdx.x == 0) mean[bc] = red[0] * (1.0f / HW);
}

// ---------------- K2: GatherExcite gate folded into Wk; blocks>=2 convert Wo->bf16 ----
__global__ __launch_bounds__(256) void k_gate(const float* __restrict__ mean,
    const float* __restrict__ gw1, const float* __restrict__ gb1,
    const float* __restrict__ gw2, const float* __restrict__ gb2,
    const float* __restrict__ Wk, float* __restrict__ wkb,
    const float* __restrict__ Wo, bf16* __restrict__ wo_bf) {
  if (blockIdx.x >= 2) {                     // Wo f32 -> bf16 (65536 elems / 256 blocks)
    int i = (blockIdx.x - 2) * 256 + threadIdx.x;
    wo_bf[i] = (bf16)Wo[i];
    return;
  }
  int b = blockIdx.x;
  int t = threadIdx.x;                        // = channel c
  __shared__ float ms[CH];
  __shared__ float hid[RD];
  ms[t] = mean[b * CH + t];
  __syncthreads();
  if (t < RD) {
    float a = gb1[t];
    for (int c = 0; c < CH; ++c) a += gw1[t * CH + c] * ms[c];
    hid[t] = fmaxf(a, 0.f);
  }
  __syncthreads();
  float a = gb2[t];
  #pragma unroll
  for (int r = 0; r < RD; ++r) a += gw2[t * RD + r] * hid[r];
  float s = 1.f / (1.f + __expf(-a));         // sigmoid gate for channel t
  for (int kk = 0; kk < KC; ++kk)
    wkb[((size_t)b * KC + kk) * CH + t] = Wk[kk * CH + t] * s;
}

// ---------------- K3: fused 1x1 projections  ----------------
__global__ __launch_bounds__(256, 2) void k_proj(
    const float* __restrict__ x, const float* __restrict__ Wq,
    const float* __restrict__ wkb, const float* __restrict__ Wb1,
    const float* __restrict__ Wb2, const float* __restrict__ Wv,
    bf16* __restrict__ qt, bf16* __restrict__ kt,
    bf16* __restrict__ b1r, bf16* __restrict__ b2r, bf16* __restrict__ vt) {
  __shared__ __align__(16) float xs[CH * 36];
  const int blk  = blockIdx.x;
  const int half = blk & 1;
  const int nn   = (blk >> 1) & 127;
  const int b    = blk >> 8;
  const int n0   = nn * 32;
  const int t    = threadIdx.x;
  {
    const int j = t & 31, crow = t >> 5;
    const float* xb = x + ((size_t)b * CH) * HW + n0;
    #pragma unroll
    for (int i = 0; i < 32; ++i) {
      int c = crow + 8 * i;
      xs[c * 36 + j] = xb[(size_t)c * HW + j];
    }
  }
  __syncthreads();
  const int og = t >> 3;
  const int jg = t & 7;
  const float* wkb_b = wkb + (size_t)b * KC * CH;
  const float* wp[6];
  #pragma unroll
  for (int oo = 0; oo < 6; ++oo) {
    int o = half * 192 + og * 6 + oo;
    const float* w;
    if (o < 32)       w = Wq   + o * CH;
    else if (o < 64)  w = wkb_b + (o - 32) * CH;
    else if (o < 96)  w = Wb1  + (o - 64) * CH;
    else if (o < 128) w = Wb2  + (o - 96) * CH;
    else              w = Wv   + (o - 128) * CH;
    wp[oo] = w;
  }
  float acc[6][4];
  #pragma unroll
  for (int oo = 0; oo < 6; ++oo)
    #pragma unroll
    for (int jj = 0; jj < 4; ++jj) acc[oo][jj] = 0.f;
  for (int c0 = 0; c0 < CH; c0 += 4) {
    v4f xv[4];
    #pragma unroll
    for (int cc = 0; cc < 4; ++cc)
      xv[cc] = *(const v4f*)&xs[(c0 + cc) * 36 + jg * 4];
    #pragma unroll
    for (int oo = 0; oo < 6; ++oo) {
      v4f wv = *(const v4f*)(wp[oo] + c0);
      #pragma unroll
      for (int cc = 0; cc < 4; ++cc)
        #pragma unroll
        for (int jj = 0; jj < 4; ++jj)
          acc[oo][jj] += wv[cc] * xv[cc][jj];
    }
  }
  #pragma unroll
  for (int oo = 0; oo < 6; ++oo) {
    int o = half * 192 + og * 6 + oo;
    #pragma unroll
    for (int jj = 0; jj < 4; ++jj) {
      int n = n0 + jg * 4 + jj;
      size_t nb = (size_t)b * HW + n;
      float v = acc[oo][jj];
      if (o < 32)       qt[nb * KC + o] = (bf16)(v * LOG2E);   // exp2-folded
      else if (o < 64)  kt[nb * KC + (o - 32)] = (bf16)v;
      else if (o < 96)  b1r[nb * KC + (o - 64)] = (bf16)fmaxf(v, 0.f);
      else if (o < 128) b2r[nb * KC + (o - 96)] = (bf16)fmaxf(v, 0.f);
      else              vt[((size_t)b * CH + (o - 128)) * VSTRIDE + n] = (bf16)v;
    }
  }
}

// ---------------- K3b: 1-D 3-tap pool (-log2e*w_gb/9 folded into bs1) ----------------
__global__ __launch_bounds__(256) void k_pool(const bf16* __restrict__ b1r,
    const bf16* __restrict__ b2r, const float* __restrict__ wgb,
    bf16* __restrict__ bs1, bf16* __restrict__ bs2) {
  int i = blockIdx.x * 256 + threadIdx.x;
  int n = (i >> 5) & (HW - 1);
  float a = (float)b1r[i], c = (float)b2r[i];
  if (n > 0)      { a += (float)b1r[i - KC]; c += (float)b2r[i - KC]; }
  if (n < HW - 1) { a += (float)b1r[i + KC]; c += (float)b2r[i + KC]; }
  const float ws = -LOG2E * wgb[0] * (1.f / 9.f);
  bs1[i] = (bf16)(a * ws);
  bs2[i] = (bf16)c;
}

// ---------------- K4: flash attention, swapped QK + single-buffered K + split-8 ------
// blk = rt*8 + os; rt = 64-row tile (b = rt>>6), os = key-split (512 keys, 8 steps x 64).
// 4 waves; wave w owns rows [w*16, +16).
__global__ __launch_bounds__(256, 3) void k_attn(
    const bf16* __restrict__ qtg, const bf16* __restrict__ ktg,
    const bf16* __restrict__ bs1g, const bf16* __restrict__ bs2g,
    const bf16* __restrict__ vtg,
    bf16* __restrict__ pacc, float* __restrict__ pl) {
  __shared__ __align__(16) bf16 vbuf[256][64];    // V tile, 128B rows, XOR slot swizzle
  __shared__ __align__(16) bf16 kbuf[64][40];     // K tile (single buffer; barrier-safe)
  __shared__ __align__(16) bf16 bbuf[64][40];     // B2 tile
  __shared__ __align__(16) bf16 plds[4][16][72];  // per-wave P [qrow][key]
  const int blk = blockIdx.x;
  const int rt  = blk >> 3;
  const int os  = blk & 7;
  const int b   = rt >> 6;
  const int row0 = (rt & 63) * 64;
  const int w    = threadIdx.x >> 6;
  const int lane = threadIdx.x & 63;
  const int cl = lane & 15;
  const int kh = lane >> 4;
  const int kb = os * 512;
  const v4f vzero = {0.f, 0.f, 0.f, 0.f};
  const size_t qoff = ((size_t)(b * HW + row0 + w * 16 + cl)) * KC + kh * 8;
  const v8bf qf  = *(const v8bf*)(qtg + qoff);    // B-frag: col = qrow (cl)
  const v8bf b1f = *(const v8bf*)(bs1g + qoff);
  const bf16* kt = ktg + (size_t)b * HW * KC;
  const bf16* b2 = bs2g + (size_t)b * HW * KC;
  const bf16* vt = vtg + (size_t)b * CH * VSTRIDE;
  // staging lane roles
  const int krow = w * 16 + (lane >> 2), kslot = (lane & 3) * 8;   // K/B2: 16 rows/wave
  const int vch   = w * 64 + (lane >> 3);                          // V: 64 ch/wave (+i*8)
  const int vslog = lane & 7;                                      // logical 16B slot
  const int vwr   = (vslog ^ (lane >> 3)) * 8;                     // swizzled write slot
  const int x7 = cl & 7;
  const int ro0 = (kh ^ x7) * 8;                                   // swizzled read slots
  const int ro1 = ((kh + 4) ^ x7) * 8;

  // prologue: stage K/B2 for step 0
  *(v8bf*)&kbuf[krow][kslot] = *(const v8bf*)(kt + (size_t)(kb + krow) * KC + kslot);
  *(v8bf*)&bbuf[krow][kslot] = *(const v8bf*)(b2 + (size_t)(kb + krow) * KC + kslot);
  __syncthreads();

  v4f acc[16];
  #pragma unroll
  for (int f = 0; f < 16; ++f) acc[f] = vzero;
  float psum = 0.f;

  for (int s = 0; s < 8; ++s) {
    const int m0 = kb + s * 64;
    // issue V tile loads (consumed after QK)
    v8bf vr[8];
    #pragma unroll
    for (int i = 0; i < 8; ++i)
      vr[i] = *(const v8bf*)(vt + (size_t)(vch + i * 8) * VSTRIDE + m0 + vslog * 8);
    // issue next-step K/B2 loads
    v8bf kr, br;
    if (s < 7) {
      kr = *(const v8bf*)(kt + (size_t)(m0 + 64 + krow) * KC + kslot);
      br = *(const v8bf*)(b2 + (size_t)(m0 + 64 + krow) * KC + kslot);
    }
    // swapped QK: C[key][qrow] -> lane owns 16 keys of ITS OWN row (w*16+cl)
    #pragma unroll
    for (int cb = 0; cb < 4; ++cb) {
      v8bf kf  = *(const v8bf*)&kbuf[cb * 16 + cl][kh * 8];
      v8bf b2f = *(const v8bf*)&bbuf[cb * 16 + cl][kh * 8];
      v4f sim = __builtin_amdgcn_mfma_f32_16x16x32_bf16(kf,  qf,  vzero, 0, 0, 0);
      v4f bia = __builtin_amdgcn_mfma_f32_16x16x32_bf16(b2f, b1f, vzero, 0, 0, 0);
      v4bf pk;
      #pragma unroll
      for (int r = 0; r < 4; ++r) {
        float bm = frcp(1.f + fexp2(bia[r]));      // sigmoid; -log2e pre-folded
        float pv = fexp2(sim[r] * bm);             // exp; log2e pre-folded in qt
        psum += pv;
        pk[r] = (bf16)pv;
      }
      *(v4bf*)&plds[w][cl][cb * 16 + kh * 4] = pk; // keys cb*16+kh*4.. contiguous 8B
    }
    asm volatile("s_waitcnt lgkmcnt(0)" ::: "memory");
    __builtin_amdgcn_sched_barrier(0);
    const v8bf pa0 = *(const v8bf*)&plds[w][cl][kh * 8];
    const v8bf pa1 = *(const v8bf*)&plds[w][cl][32 + kh * 8];
    // stage V tile (swizzled write)
    #pragma unroll
    for (int i = 0; i < 8; ++i)
      *(v8bf*)&vbuf[vch + i * 8][vwr] = vr[i];
    __syncthreads();                          // [A] all QK reads of kbuf done; vbuf ready
    // PV from LDS (swizzled read)
    #pragma unroll
    for (int f = 0; f < 16; ++f) {
      v8bf v0 = *(const v8bf*)&vbuf[f * 16 + cl][ro0];
      v8bf v1 = *(const v8bf*)&vbuf[f * 16 + cl][ro1];
      acc[f] = __builtin_amdgcn_mfma_f32_16x16x32_bf16(pa0, v0, acc[f], 0, 0, 0);
      acc[f] = __builtin_amdgcn_mfma_f32_16x16x32_bf16(pa1, v1, acc[f], 0, 0, 0);
    }
    // stage next K/B2 in place (safe after barrier A)
    if (s < 7) {
      *(v8bf*)&kbuf[krow][kslot] = kr;
      *(v8bf*)&bbuf[krow][kslot] = br;
    }
    __syncthreads();                          // [B] vbuf consumed + next K visible
  }

  // ---- epilogue ----
  {
    float s2 = psum;
    s2 += __shfl_xor(s2, 16);
    s2 += __shfl_xor(s2, 32);
    if (kh == 0) pl[blk * 64 + w * 16 + cl] = s2;
  }
  // acc store via per-wave LDS transpose for coalescing
  bf16* po = pacc + (size_t)blk * 64 * CH;
  for (int c4 = 0; c4 < 4; ++c4) {
    #pragma unroll
    for (int ff = 0; ff < 4; ++ff)
      #pragma unroll
      for (int r = 0; r < 4; ++r)
        plds[w][kh * 4 + r][ff * 16 + cl] = (bf16)acc[c4 * 4 + ff][r];
    asm volatile("s_waitcnt lgkmcnt(0)" ::: "memory");
    __builtin_amdgcn_sched_barrier(0);
    #pragma unroll
    for (int it = 0; it < 2; ++it) {
      int row = lane >> 2, chunk = it * 4 + (lane & 3);
      v8bf d = *(const v8bf*)&plds[w][row][chunk * 8];
      *(v8bf*)&po[(size_t)(w * 16 + row) * CH + c4 * 64 + chunk * 8] = d;
    }
  }
}

// ---------------- K4b: split-K combine (plain sum + divide) ----------------
__global__ __launch_bounds__(256) void k_combine(const bf16* __restrict__ pacc,
    const float* __restrict__ pl, bf16* __restrict__ ctx) {
  const int r = blockIdx.x * 4 + (threadIdx.x >> 6);   // global row 0..8191
  const int lane = threadIdx.x & 63;
  const int rt = r >> 6;
  const int rl = r & 63;
  const int base = rt * 8;
  float den = 0.f;
  #pragma unroll
  for (int s = 0; s < 8; ++s) den += pl[(base + s) * 64 + rl];
  const float inv = 1.f / den;
  #pragma unroll
  for (int c0 = 0; c0 < CH; c0 += 64) {
    int c = c0 + lane;
    float a = 0.f;
    #pragma unroll
    for (int s = 0; s < 8; ++s)
      a += (float)pacc[((size_t)(base + s) * 64 + rl) * CH + c];
    ctx[(size_t)r * CH + c] = (bf16)(a * inv);
  }
}

// ---------------- K5: output 1x1 conv (MFMA) + BN + ReLU + residual ----------------
// 512 blocks x 16 rows; 4 waves, wave w -> cout [w*64, +64)
__global__ __launch_bounds__(256) void k_out(
    const bf16* __restrict__ ctx, const bf16* __restrict__ wo,
    const float* __restrict__ bns, const float* __restrict__ bnb,
    const float* __restrict__ bnm, const float* __restrict__ bnv,
    const float* __restrict__ gamma, const float* __restrict__ x,
    float* __restrict__ out) {
  const int blk = blockIdx.x;
  const int n0g = blk * 16;                 // global row
  const int b   = n0g >> 12;
  const int n0  = n0g & (HW - 1);
  const int t = threadIdx.x;
  const int w = t >> 6, lane = t & 63, cl = lane & 15, kh = lane >> 4;
  const v4f vzero = {0.f, 0.f, 0.f, 0.f};
  v8bf a[8];
  #pragma unroll
  for (int kk = 0; kk < 8; ++kk)
    a[kk] = *(const v8bf*)(ctx + (size_t)(n0g + cl) * CH + kk * 32 + kh * 8);
  v4f acc[4] = {vzero, vzero, vzero, vzero};
  #pragma unroll
  for (int kk = 0; kk < 8; ++kk)
    #pragma unroll
    for (int cg = 0; cg < 4; ++cg) {
      v8bf bfr = *(const v8bf*)(wo + (size_t)(w * 64 + cg * 16 + cl) * CH + kk * 32 + kh * 8);
      acc[cg] = __builtin_amdgcn_mfma_f32_16x16x32_bf16(a[kk], bfr, acc[cg], 0, 0, 0);
    }
  const float g = gamma[0];
  #pragma unroll
  for (int cg = 0; cg < 4; ++cg) {
    int o = w * 64 + cg * 16 + cl;
    float isc = bns[o] / sqrtf(bnv[o] + BNEPS);
    float mu = bnm[o], bb = bnb[o];
    size_t oi = ((size_t)b * CH + o) * HW + n0 + kh * 4;
    v4f xv = *(const v4f*)&x[oi];
    v4f ov;
    #pragma unroll
    for (int r = 0; r < 4; ++r) {
      float v = (acc[cg][r] - mu) * isc + bb;
      v = fmaxf(v, 0.f);
      ov[r] = g * v + xv[r];
    }
    *(v4f*)&out[oi] = ov;
  }
}

// ---------------- launch ----------------
extern "C" void kernel_launch(void* const* d_in, const int* in_sizes, int n_in,
                              void* d_out, int out_size, void* d_ws, size_t ws_size,
                              hipStream_t stream) {
  const float* x    = (const float*)d_in[0];
  const float* Wq   = (const float*)d_in[1];
  const float* Wk   = (const float*)d_in[2];
  const float* Wv   = (const float*)d_in[3];
  const float* Wb1  = (const float*)d_in[4];
  const float* Wb2  = (const float*)d_in[5];
  const float* wgb  = (const float*)d_in[6];
  const float* gw1  = (const float*)d_in[7];
  const float* gb1  = (const float*)d_in[8];
  const float* gw2  = (const float*)d_in[9];
  const float* gb2  = (const float*)d_in[10];
  const float* Wo   = (const float*)d_in[11];
  const float* bns  = (const float*)d_in[12];
  const float* bnb  = (const float*)d_in[13];
  const float* bnm  = (const float*)d_in[14];
  const float* bnv  = (const float*)d_in[15];
  const float* gam  = (const float*)d_in[16];

  char* ws = (char*)d_ws;
  float* mean = (float*)(ws + OFF_MEAN);
  float* wkb  = (float*)(ws + OFF_WKB);
  bf16* qt    = (bf16*)(ws + OFF_QT);
  bf16* kt    = (bf16*)(ws + OFF_KT);
  bf16* bs1   = (bf16*)(ws + OFF_BS1);
  bf16* bs2   = (bf16*)(ws + OFF_BS2);
  bf16* vt    = (bf16*)(ws + OFF_VT);
  bf16* b1r   = (bf16*)(ws + OFF_B1R);
  bf16* b2r   = (bf16*)(ws + OFF_B2R);
  bf16* ctx   = (bf16*)(ws + OFF_CTX);
  bf16* pacc  = (bf16*)(ws + OFF_PACC);
  float* plv  = (float*)(ws + OFF_PL);
  bf16* wobf  = (bf16*)(ws + OFF_WOBF);
  float* out  = (float*)d_out;

  hipLaunchKernelGGL(k_mean,    dim3(NB * CH),        dim3(256), 0, stream, x, mean);
  hipLaunchKernelGGL(k_gate,    dim3(2 + 256),        dim3(256), 0, stream, mean, gw1, gb1, gw2, gb2, Wk, wkb, Wo, wobf);
  hipLaunchKernelGGL(k_proj,    dim3(NB * 128 * 2),   dim3(256), 0, stream, x, Wq, wkb, Wb1, Wb2, Wv, qt, kt, b1r, b2r, vt);
  hipLaunchKernelGGL(k_pool,    dim3(NB * HW * KC / 256), dim3(256), 0, stream, b1r, b2r, wgb, bs1, bs2);
  hipLaunchKernelGGL(k_attn,    dim3(1024),           dim3(256), 0, stream, qt, kt, bs1, bs2, vt, pacc, plv);
  hipLaunchKernelGGL(k_combine, dim3(NB * HW / 4),    dim3(256), 0, stream, pacc, plv, ctx);
  hipLaunchKernelGGL(k_out,     dim3(512),            dim3(256), 0, stream, ctx, wobf, bns, bnb, bnm, bnv, gam, x, out);
}

// Round 9
// 93.082 us; speedup vs baseline: 1.3810x; 1.1407x over previous
//
#include <hip/hip_runtime.h>
#include <hip/hip_bf16.h>

typedef __bf16 bf16;
typedef __bf16 v8bf __attribute__((ext_vector_type(8)));
typedef __bf16 v4bf __attribute__((ext_vector_type(4)));
typedef float v4f __attribute__((ext_vector_type(4)));

#define HW 4096
#define CH 256
#define KC 32
#define RD 16
#define NB 2
#define BNEPS 1e-5f
#define VSTRIDE 4224
#define LOG2E 1.4426950408889634f

__device__ __forceinline__ float fexp2(float x) {
#if __has_builtin(__builtin_amdgcn_exp2f)
  return __builtin_amdgcn_exp2f(x);
#else
  return exp2f(x);
#endif
}
__device__ __forceinline__ float frcp(float x) {
#if __has_builtin(__builtin_amdgcn_rcpf)
  return __builtin_amdgcn_rcpf(x);
#else
  return 1.f / x;
#endif
}

// ---------------- workspace byte offsets (~50.3 MiB) ----------------
#define OFF_MEAN   0u          // f32 [2][256]
#define OFF_WKB    4096u       // f32 [2][32][256] gate-folded Wk
#define OFF_QT     69632u      // bf16 [2][4096][32]  (log2e folded via wall)
#define OFF_KT     593920u     // bf16 [2][4096][32]
#define OFF_BS1    1118208u    // bf16 [2][4096][32] pooled b1 (scaled -log2e*w_gb/9)
#define OFF_BS2    1642496u    // bf16 [2][4096][32] pooled b2
#define OFF_VT     2166784u    // bf16 [2][256][VSTRIDE] V transposed
#define OFF_B1R    6492160u    // bf16 [2][4096][32]
#define OFF_B2R    7016448u    // bf16 [2][4096][32]
#define OFF_CTX    7540736u    // bf16 [2][4096][256]
#define OFF_PACC   11735040u   // bf16 [1024][64][256] split-K partial ctx
#define OFF_PL     45289472u   // f32 [1024*64]
#define OFF_WOBF   45551616u   // bf16 [256][256]
#define OFF_XBT    45682688u   // bf16 [2][4096][256]  x transposed
#define OFF_WALL   49876992u   // bf16 [2][384][256]   packed proj weights

// ---------------- K1: per-(b,c) spatial mean ----------------
__global__ __launch_bounds__(256) void k_mean(const float* __restrict__ x,
                                              float* __restrict__ mean) {
  int bc = blockIdx.x;
  const float* px = x + (size_t)bc * HW;
  float s = 0.f;
  for (int i = threadIdx.x; i < HW; i += 256) s += px[i];
  __shared__ float red[256];
  red[threadIdx.x] = s; __syncthreads();
  for (int st = 128; st > 0; st >>= 1) {
    if (threadIdx.x < st) red[threadIdx.x] += red[threadIdx.x + st];
    __syncthreads();
  }
  if (threadIdx.x == 0) mean[bc] = red[0] * (1.0f / HW);
}

// ---------------- K2: gate folded into Wk; blocks>=2 convert Wo->bf16 ----------------
__global__ __launch_bounds__(256) void k_gate(const float* __restrict__ mean,
    const float* __restrict__ gw1, const float* __restrict__ gb1,
    const float* __restrict__ gw2, const float* __restrict__ gb2,
    const float* __restrict__ Wk, float* __restrict__ wkb,
    const float* __restrict__ Wo, bf16* __restrict__ wo_bf) {
  if (blockIdx.x >= 2) {
    int i = (blockIdx.x - 2) * 256 + threadIdx.x;
    wo_bf[i] = (bf16)Wo[i];
    return;
  }
  int b = blockIdx.x;
  int t = threadIdx.x;
  __shared__ float ms[CH];
  __shared__ float hid[RD];
  ms[t] = mean[b * CH + t];
  __syncthreads();
  if (t < RD) {
    float a = gb1[t];
    for (int c = 0; c < CH; ++c) a += gw1[t * CH + c] * ms[c];
    hid[t] = fmaxf(a, 0.f);
  }
  __syncthreads();
  float a = gb2[t];
  #pragma unroll
  for (int r = 0; r < RD; ++r) a += gw2[t * RD + r] * hid[r];
  float s = 1.f / (1.f + __expf(-a));
  for (int kk = 0; kk < KC; ++kk)
    wkb[((size_t)b * KC + kk) * CH + t] = Wk[kk * CH + t] * s;
}

// ---------------- K2b: prep — transpose x to bf16 [n][c]; pack wall weights ---------
__global__ __launch_bounds__(256) void k_prep(const float* __restrict__ x,
    const float* __restrict__ Wq, const float* __restrict__ wkb,
    const float* __restrict__ Wb1, const float* __restrict__ Wb2,
    const float* __restrict__ Wv,
    bf16* __restrict__ xbt, bf16* __restrict__ wall) {
  __shared__ __align__(16) float ts[64][68];
  const int blk = blockIdx.x;
  const int t = threadIdx.x;
  if (blk < 512) {                       // 64c x 64n transpose tiles
    const int b  = blk >> 8;
    const int id = blk & 255;
    const int ct = id >> 6, nt = id & 63;
    const int c0 = ct * 64, n0 = nt * 64;
    const int crow = t >> 2, nch = (t & 3) * 16;
    const float* xp = x + ((size_t)(b * CH + c0 + crow)) * HW + n0 + nch;
    #pragma unroll
    for (int i = 0; i < 4; ++i)
      *(v4f*)&ts[crow][nch + i * 4] = *(const v4f*)(xp + i * 4);
    __syncthreads();
    const int nl = t >> 2, cc0 = (t & 3) * 16;
    bf16* dst = xbt + ((size_t)(b * HW + n0 + nl)) * CH + c0 + cc0;
    v8bf o0, o1;
    #pragma unroll
    for (int j = 0; j < 8; ++j) { o0[j] = (bf16)ts[cc0 + j][nl]; o1[j] = (bf16)ts[cc0 + 8 + j][nl]; }
    *(v8bf*)dst = o0;
    *(v8bf*)(dst + 8) = o1;
  } else {                               // pack wall[2][384][256]
    const int idx = blk - 512;           // 0..767
    const int b = idx / 384, row = idx % 384;
    float v;
    if (row < 32)       v = Wq[row * CH + t] * LOG2E;
    else if (row < 64)  v = wkb[((size_t)b * KC + row - 32) * CH + t];
    else if (row < 96)  v = Wb1[(row - 64) * CH + t];
    else if (row < 128) v = Wb2[(row - 96) * CH + t];
    else                v = Wv[(row - 128) * CH + t];
    wall[((size_t)b * 384 + row) * CH + t] = (bf16)v;
  }
}

// ---------------- K3: fused 1x1 projections via MFMA ----------------
// blk = b*512 + bm*128 + nt : bm = 96-row weight slice, nt = 32-col n tile.
// 4 waves: wave w -> otile trio (w>>1)*3, n-sub (w&1)*16.
__global__ __launch_bounds__(256, 4) void k_proj(
    const bf16* __restrict__ xbt, const bf16* __restrict__ wall,
    bf16* __restrict__ qt, bf16* __restrict__ kt,
    bf16* __restrict__ b1r, bf16* __restrict__ b2r, bf16* __restrict__ vt) {
  __shared__ __align__(16) bf16 xs[32][264];
  __shared__ __align__(16) bf16 tr[4][16][24];
  const int blk = blockIdx.x;
  const int b  = blk >> 9;
  const int bm = (blk >> 7) & 3;
  const int nt = blk & 127;
  const int n0 = nt * 32;
  const int t = threadIdx.x;
  {
    const int row = t >> 3, c0 = (t & 7) * 32;
    const bf16* src = xbt + ((size_t)(b * HW + n0 + row)) * CH + c0;
    #pragma unroll
    for (int i = 0; i < 4; ++i)
      *(v8bf*)&xs[row][c0 + i * 8] = *(const v8bf*)(src + i * 8);
  }
  __syncthreads();
  const int w = t >> 6, lane = t & 63, cl = lane & 15, kh = lane >> 4;
  const int nsub = (w & 1) * 16;
  const int otrio = (w >> 1) * 3;
  const v4f vzero = {0.f, 0.f, 0.f, 0.f};
  v4f acc[3] = {vzero, vzero, vzero};
  const bf16* wb = wall + ((size_t)b * 384 + bm * 96) * CH;
  for (int kk = 0; kk < 8; ++kk) {
    v8bf bx = *(const v8bf*)&xs[nsub + cl][kk * 32 + kh * 8];
    #pragma unroll
    for (int j = 0; j < 3; ++j) {
      v8bf af = *(const v8bf*)(wb + (size_t)((otrio + j) * 16 + cl) * CH + kk * 32 + kh * 8);
      acc[j] = __builtin_amdgcn_mfma_f32_16x16x32_bf16(af, bx, acc[j], 0, 0, 0);
    }
  }
  const int n = n0 + nsub + cl;
  #pragma unroll
  for (int j = 0; j < 3; ++j) {
    const int o0 = bm * 96 + (otrio + j) * 16;    // wall row base of this tile
    if (o0 < 128) {                                // q/k/b1/b2: [n][32] layout
      const bool rel = (o0 >= 64);
      v4bf pk;
      #pragma unroll
      for (int r = 0; r < 4; ++r) {
        float v = acc[j][r];
        if (rel) v = fmaxf(v, 0.f);
        pk[r] = (bf16)v;
      }
      const int seg = o0 >> 5;
      bf16* base = seg == 0 ? qt : seg == 1 ? kt : seg == 2 ? b1r : b2r;
      *(v4bf*)&base[((size_t)b * HW + n) * KC + (o0 & 31) + kh * 4] = pk;
    } else {                                       // v: transpose -> vt[ch][n]
      #pragma unroll
      for (int r = 0; r < 4; ++r) tr[w][kh * 4 + r][cl] = (bf16)acc[j][r];
      asm volatile("s_waitcnt lgkmcnt(0)" ::: "memory");
      __builtin_amdgcn_sched_barrier(0);
      const int row = lane >> 2, nch = (lane & 3) * 4;
      v4bf d = *(const v4bf*)&tr[w][row][nch];
      *(v4bf*)&vt[((size_t)b * CH + (o0 - 128) + row) * VSTRIDE + n0 + nsub + nch] = d;
    }
  }
}

// ---------------- K3b: 1-D 3-tap pool (-log2e*w_gb/9 folded into bs1) ----------------
__global__ __launch_bounds__(256) void k_pool(const bf16* __restrict__ b1r,
    const bf16* __restrict__ b2r, const float* __restrict__ wgb,
    bf16* __restrict__ bs1, bf16* __restrict__ bs2) {
  int i = blockIdx.x * 256 + threadIdx.x;
  int n = (i >> 5) & (HW - 1);
  float a = (float)b1r[i], c = (float)b2r[i];
  if (n > 0)      { a += (float)b1r[i - KC]; c += (float)b2r[i - KC]; }
  if (n < HW - 1) { a += (float)b1r[i + KC]; c += (float)b2r[i + KC]; }
  const float ws = -LOG2E * wgb[0] * (1.f / 9.f);
  bs1[i] = (bf16)(a * ws);
  bs2[i] = (bf16)c;
}

// ---------------- K4: flash attention — row-split QK, channel-split PV ----------------
// blk = rt*8 + os; 64-row tile, 512-key split, 8 steps of 64 keys.
// QK: wave w computes P rows [w*16,+16) (lane-local). PV: wave w computes
// ALL 64 rows x channels [w*64,+64) -> V LDS reads cut 4x vs row-split PV.
__global__ __launch_bounds__(256, 3) void k_attn(
    const bf16* __restrict__ qtg, const bf16* __restrict__ ktg,
    const bf16* __restrict__ bs1g, const bf16* __restrict__ bs2g,
    const bf16* __restrict__ vtg,
    bf16* __restrict__ pacc, float* __restrict__ pl) {
  __shared__ __align__(16) bf16 vbuf[256][64];    // V tile, XOR slot swizzle
  __shared__ __align__(16) bf16 kbuf[64][40];     // K tile (single buffer)
  __shared__ __align__(16) bf16 bbuf[64][40];     // B2 tile
  __shared__ __align__(16) bf16 plds[64][72];     // shared P [qrow][key]
  const int blk = blockIdx.x;
  const int rt  = blk >> 3;
  const int os  = blk & 7;
  const int b   = rt >> 6;
  const int row0 = (rt & 63) * 64;
  const int w    = threadIdx.x >> 6;
  const int lane = threadIdx.x & 63;
  const int cl = lane & 15;
  const int kh = lane >> 4;
  const int kb = os * 512;
  const v4f vzero = {0.f, 0.f, 0.f, 0.f};
  const size_t qoff = ((size_t)(b * HW + row0 + w * 16 + cl)) * KC + kh * 8;
  const v8bf qf  = *(const v8bf*)(qtg + qoff);    // B-frag: col = qrow
  const v8bf b1f = *(const v8bf*)(bs1g + qoff);
  const bf16* kt = ktg + (size_t)b * HW * KC;
  const bf16* b2 = bs2g + (size_t)b * HW * KC;
  const bf16* vt = vtg + (size_t)b * CH * VSTRIDE;
  // staging roles
  const int krow = w * 16 + (lane >> 2), kslot = (lane & 3) * 8;
  const int vch   = w * 64 + (lane >> 3);
  const int vslog = lane & 7;
  const int vwr   = (vslog ^ (lane >> 3)) * 8;
  const int x7 = cl & 7;
  const int ro0 = (kh ^ x7) * 8;
  const int ro1 = ((kh + 4) ^ x7) * 8;

  *(v8bf*)&kbuf[krow][kslot] = *(const v8bf*)(kt + (size_t)(kb + krow) * KC + kslot);
  *(v8bf*)&bbuf[krow][kslot] = *(const v8bf*)(b2 + (size_t)(kb + krow) * KC + kslot);
  __syncthreads();

  v4f acc[16];                                    // [rg][f]: rows rg*16.., ch w*64+f*16..
  #pragma unroll
  for (int f = 0; f < 16; ++f) acc[f] = vzero;
  float psum = 0.f;

  for (int s = 0; s < 8; ++s) {
    const int m0 = kb + s * 64;
    v8bf vr[8];
    #pragma unroll
    for (int i = 0; i < 8; ++i)
      vr[i] = *(const v8bf*)(vt + (size_t)(vch + i * 8) * VSTRIDE + m0 + vslog * 8);
    v8bf kr, br;
    if (s < 7) {
      kr = *(const v8bf*)(kt + (size_t)(m0 + 64 + krow) * KC + kslot);
      br = *(const v8bf*)(b2 + (size_t)(m0 + 64 + krow) * KC + kslot);
    }
    // swapped QK: lane owns 16 keys of its own row (w*16+cl); write shared P
    #pragma unroll
    for (int cb = 0; cb < 4; ++cb) {
      v8bf kf  = *(const v8bf*)&kbuf[cb * 16 + cl][kh * 8];
      v8bf b2f = *(const v8bf*)&bbuf[cb * 16 + cl][kh * 8];
      v4f sim = __builtin_amdgcn_mfma_f32_16x16x32_bf16(kf,  qf,  vzero, 0, 0, 0);
      v4f bia = __builtin_amdgcn_mfma_f32_16x16x32_bf16(b2f, b1f, vzero, 0, 0, 0);
      v4bf pk;
      #pragma unroll
      for (int r = 0; r < 4; ++r) {
        float bm = frcp(1.f + fexp2(bia[r]));
        float pv = fexp2(sim[r] * bm);
        psum += pv;
        pk[r] = (bf16)pv;
      }
      *(v4bf*)&plds[w * 16 + cl][cb * 16 + kh * 4] = pk;
    }
    // stage V tile (swizzled write)
    #pragma unroll
    for (int i = 0; i < 8; ++i)
      *(v8bf*)&vbuf[vch + i * 8][vwr] = vr[i];
    __syncthreads();                              // [A] P + V visible to all waves
    // V frags for my 64-channel slice
    v8bf vf[8];
    #pragma unroll
    for (int f = 0; f < 4; ++f) {
      vf[f * 2 + 0] = *(const v8bf*)&vbuf[w * 64 + f * 16 + cl][ro0];
      vf[f * 2 + 1] = *(const v8bf*)&vbuf[w * 64 + f * 16 + cl][ro1];
    }
    // PV over ALL 64 rows
    #pragma unroll
    for (int rg = 0; rg < 4; ++rg) {
      v8bf pa0 = *(const v8bf*)&plds[rg * 16 + cl][kh * 8];
      v8bf pa1 = *(const v8bf*)&plds[rg * 16 + cl][32 + kh * 8];
      #pragma unroll
      for (int f = 0; f < 4; ++f) {
        acc[rg * 4 + f] = __builtin_amdgcn_mfma_f32_16x16x32_bf16(pa0, vf[f * 2 + 0], acc[rg * 4 + f], 0, 0, 0);
        acc[rg * 4 + f] = __builtin_amdgcn_mfma_f32_16x16x32_bf16(pa1, vf[f * 2 + 1], acc[rg * 4 + f], 0, 0, 0);
      }
    }
    if (s < 7) {
      *(v8bf*)&kbuf[krow][kslot] = kr;
      *(v8bf*)&bbuf[krow][kslot] = br;
    }
    __syncthreads();                              // [B] consumed; next K visible
  }

  // ---- epilogue ----
  {
    float s2 = psum;
    s2 += __shfl_xor(s2, 16);
    s2 += __shfl_xor(s2, 32);
    if (kh == 0) pl[blk * 64 + w * 16 + cl] = s2;
  }
  // store acc: wave w owns ch slice [w*64,+64) for all 64 rows; transpose per rg
  bf16* po = pacc + (size_t)blk * 64 * CH;
  for (int rg = 0; rg < 4; ++rg) {
    #pragma unroll
    for (int f = 0; f < 4; ++f)
      #pragma unroll
      for (int r = 0; r < 4; ++r)
        plds[w * 16 + kh * 4 + r][f * 16 + cl] = (bf16)acc[rg * 4 + f][r];
    asm volatile("s_waitcnt lgkmcnt(0)" ::: "memory");
    __builtin_amdgcn_sched_barrier(0);
    #pragma unroll
    for (int it = 0; it < 2; ++it) {
      int row = lane >> 2, chunk = it * 4 + (lane & 3);
      v8bf d = *(const v8bf*)&plds[w * 16 + row][chunk * 8];
      *(v8bf*)&po[(size_t)(rg * 16 + row) * CH + w * 64 + chunk * 8] = d;
    }
  }
}

// ---------------- K4b: split-K combine ----------------
__global__ __launch_bounds__(256) void k_combine(const bf16* __restrict__ pacc,
    const float* __restrict__ pl, bf16* __restrict__ ctx) {
  const int r = blockIdx.x * 4 + (threadIdx.x >> 6);
  const int lane = threadIdx.x & 63;
  const int rt = r >> 6;
  const int rl = r & 63;
  const int base = rt * 8;
  float den = 0.f;
  #pragma unroll
  for (int s = 0; s < 8; ++s) den += pl[(base + s) * 64 + rl];
  const float inv = 1.f / den;
  #pragma unroll
  for (int c0 = 0; c0 < CH; c0 += 64) {
    int c = c0 + lane;
    float a = 0.f;
    #pragma unroll
    for (int s = 0; s < 8; ++s)
      a += (float)pacc[((size_t)(base + s) * 64 + rl) * CH + c];
    ctx[(size_t)r * CH + c] = (bf16)(a * inv);
  }
}

// ---------------- K5: output 1x1 conv (MFMA) + BN + ReLU + residual ----------------
__global__ __launch_bounds__(256) void k_out(
    const bf16* __restrict__ ctx, const bf16* __restrict__ wo,
    const float* __restrict__ bns, const float* __restrict__ bnb,
    const float* __restrict__ bnm, const float* __restrict__ bnv,
    const float* __restrict__ gamma, const float* __restrict__ x,
    float* __restrict__ out) {
  const int blk = blockIdx.x;
  const int n0g = blk * 16;
  const int b   = n0g >> 12;
  const int n0  = n0g & (HW - 1);
  const int t = threadIdx.x;
  const int w = t >> 6, lane = t & 63, cl = lane & 15, kh = lane >> 4;
  const v4f vzero = {0.f, 0.f, 0.f, 0.f};
  v8bf a[8];
  #pragma unroll
  for (int kk = 0; kk < 8; ++kk)
    a[kk] = *(const v8bf*)(ctx + (size_t)(n0g + cl) * CH + kk * 32 + kh * 8);
  v4f acc[4] = {vzero, vzero, vzero, vzero};
  #pragma unroll
  for (int kk = 0; kk < 8; ++kk)
    #pragma unroll
    for (int cg = 0; cg < 4; ++cg) {
      v8bf bfr = *(const v8bf*)(wo + (size_t)(w * 64 + cg * 16 + cl) * CH + kk * 32 + kh * 8);
      acc[cg] = __builtin_amdgcn_mfma_f32_16x16x32_bf16(a[kk], bfr, acc[cg], 0, 0, 0);
    }
  const float g = gamma[0];
  #pragma unroll
  for (int cg = 0; cg < 4; ++cg) {
    int o = w * 64 + cg * 16 + cl;
    float isc = bns[o] / sqrtf(bnv[o] + BNEPS);
    float mu = bnm[o], bb = bnb[o];
    size_t oi = ((size_t)b * CH + o) * HW + n0 + kh * 4;
    v4f xv = *(const v4f*)&x[oi];
    v4f ov;
    #pragma unroll
    for (int r = 0; r < 4; ++r) {
      float v = (acc[cg][r] - mu) * isc + bb;
      v = fmaxf(v, 0.f);
      ov[r] = g * v + xv[r];
    }
    *(v4f*)&out[oi] = ov;
  }
}

// ---------------- launch ----------------
extern "C" void kernel_launch(void* const* d_in, const int* in_sizes, int n_in,
                              void* d_out, int out_size, void* d_ws, size_t ws_size,
                              hipStream_t stream) {
  const float* x    = (const float*)d_in[0];
  const float* Wq   = (const float*)d_in[1];
  const float* Wk   = (const float*)d_in[2];
  const float* Wv   = (const float*)d_in[3];
  const float* Wb1  = (const float*)d_in[4];
  const float* Wb2  = (const float*)d_in[5];
  const float* wgb  = (const float*)d_in[6];
  const float* gw1  = (const float*)d_in[7];
  const float* gb1  = (const float*)d_in[8];
  const float* gw2  = (const float*)d_in[9];
  const float* gb2  = (const float*)d_in[10];
  const float* Wo   = (const float*)d_in[11];
  const float* bns  = (const float*)d_in[12];
  const float* bnb  = (const float*)d_in[13];
  const float* bnm  = (const float*)d_in[14];
  const float* bnv  = (const float*)d_in[15];
  const float* gam  = (const float*)d_in[16];

  char* ws = (char*)d_ws;
  float* mean = (float*)(ws + OFF_MEAN);
  float* wkb  = (float*)(ws + OFF_WKB);
  bf16* qt    = (bf16*)(ws + OFF_QT);
  bf16* kt    = (bf16*)(ws + OFF_KT);
  bf16* bs1   = (bf16*)(ws + OFF_BS1);
  bf16* bs2   = (bf16*)(ws + OFF_BS2);
  bf16* vt    = (bf16*)(ws + OFF_VT);
  bf16* b1r   = (bf16*)(ws + OFF_B1R);
  bf16* b2r   = (bf16*)(ws + OFF_B2R);
  bf16* ctx   = (bf16*)(ws + OFF_CTX);
  bf16* pacc  = (bf16*)(ws + OFF_PACC);
  float* plv  = (float*)(ws + OFF_PL);
  bf16* wobf  = (bf16*)(ws + OFF_WOBF);
  bf16* xbt   = (bf16*)(ws + OFF_XBT);
  bf16* wall  = (bf16*)(ws + OFF_WALL);
  float* out  = (float*)d_out;

  hipLaunchKernelGGL(k_mean,    dim3(NB * CH),        dim3(256), 0, stream, x, mean);
  hipLaunchKernelGGL(k_gate,    dim3(2 + 256),        dim3(256), 0, stream, mean, gw1, gb1, gw2, gb2, Wk, wkb, Wo, wobf);
  hipLaunchKernelGGL(k_prep,    dim3(512 + 768),      dim3(256), 0, stream, x, Wq, wkb, Wb1, Wb2, Wv, xbt, wall);
  hipLaunchKernelGGL(k_proj,    dim3(1024),           dim3(256), 0, stream, xbt, wall, qt, kt, b1r, b2r, vt);
  hipLaunchKernelGGL(k_pool,    dim3(NB * HW * KC / 256), dim3(256), 0, stream, b1r, b2r, wgb, bs1, bs2);
  hipLaunchKernelGGL(k_attn,    dim3(1024),           dim3(256), 0, stream, qt, kt, bs1, bs2, vt, pacc, plv);
  hipLaunchKernelGGL(k_combine, dim3(NB * HW / 4),    dim3(256), 0, stream, pacc, plv, ctx);
  hipLaunchKernelGGL(k_out,     dim3(512),            dim3(256), 0, stream, ctx, wobf, bns, bnb, bnm, bnv, gam, x, out);
}